// Round 1
// baseline (502.181 us; speedup 1.0000x reference)
//
#include <hip/hip_runtime.h>
#include <hip/hip_fp16.h>

// Fused MSE + SSIM loss, 32x3x512x512 fp32.
// Separable 11x11 gaussian conv on 5 fields (p, t, p*p, t*t, p*t) done per-tile:
//   stage1: global -> LDS halo (fp32), MSE partial folded in (interior only)
//   stage2: horizontal 11-tap pass (fp32), packed to fp16 pairs in LDS
//   stage3: vertical 11-tap pass (packed v_pk_fma_f16), SSIM map, block reduce
// Tile: 64(W) x 32(H) per 256-thread block. LDS ~52KB -> 3 blocks/CU.

#define WSZ   512
#define TW    64
#define TH    32
#define HALO  5
#define IN_W  (TW + 2*HALO)   // 74
#define IN_H  (TH + 2*HALO)   // 42
#define SPITCH 75             // odd pitch: kills stage-2 bank conflicts
#define HPW   (TW/2)          // 32 half2-pairs per hp row
#define FS    (IN_H * HPW)    // per-field half2 count in LDS (1344, even)
#define SSIM_C1 0.0001f
#define SSIM_C2 0.0009f

__launch_bounds__(256, 3)
__global__ void fused_mse_ssim(const float* __restrict__ P,
                               const float* __restrict__ T,
                               float* __restrict__ ws) {
    __shared__ float sP[IN_H * SPITCH];
    __shared__ float sT[IN_H * SPITCH];
    __shared__ float sHP[5 * FS];     // each float holds one __half2 (2 x-values)
    __shared__ float red[2][4];

    const int tid = threadIdx.x;
    const int gx0 = blockIdx.x * TW;
    const int gy0 = blockIdx.y * TH;
    const size_t plane = (size_t)blockIdx.z * (WSZ * (size_t)WSZ);
    const float* Pp = P + plane;
    const float* Tp = T + plane;

    // gaussian weights (match numpy: exp(-c^2 / (2*1.5^2)), normalized)
    float gw[11];
    {
        float s = 0.f;
        #pragma unroll
        for (int i = 0; i < 11; ++i) {
            float d = (float)(i - 5);
            gw[i] = expf(-(d * d) / 4.5f);
            s += gw[i];
        }
        float inv = 1.f / s;
        #pragma unroll
        for (int i = 0; i < 11; ++i) gw[i] *= inv;
    }

    // ---- stage 1: load halo into LDS, MSE partial on interior pixels ----
    float mse = 0.f;
    for (int i = tid; i < IN_H * IN_W; i += 256) {
        int r = i / IN_W;
        int c = i - r * IN_W;
        int gy = gy0 - HALO + r;
        int gx = gx0 - HALO + c;
        float pv = 0.f, tv = 0.f;
        if ((unsigned)gy < (unsigned)WSZ && (unsigned)gx < (unsigned)WSZ) {
            size_t o = (size_t)gy * WSZ + gx;
            pv = Pp[o];
            tv = Tp[o];
        }
        sP[r * SPITCH + c] = pv;
        sT[r * SPITCH + c] = tv;
        if ((unsigned)(r - HALO) < (unsigned)TH && (unsigned)(c - HALO) < (unsigned)TW) {
            float d = pv - tv;
            mse = fmaf(d, d, mse);
        }
    }
    __syncthreads();

    // ---- stage 2: horizontal pass, 4 outputs per item, fp32 -> fp16 pairs ----
    for (int it = tid; it < IN_H * (TW / 4); it += 256) {   // 42*16 = 672 items
        int r = it >> 4;
        int q = it & 15;
        const float* rp = &sP[r * SPITCH + q * 4];
        const float* rt = &sT[r * SPITCH + q * 4];
        float aP[4]  = {0.f, 0.f, 0.f, 0.f};
        float aT[4]  = {0.f, 0.f, 0.f, 0.f};
        float aPP[4] = {0.f, 0.f, 0.f, 0.f};
        float aTT[4] = {0.f, 0.f, 0.f, 0.f};
        float aPT[4] = {0.f, 0.f, 0.f, 0.f};
        #pragma unroll
        for (int jj = 0; jj < 14; ++jj) {
            float pv = rp[jj];
            float tv = rt[jj];
            float pp = pv * pv, tt = tv * tv, pt = pv * tv;
            #pragma unroll
            for (int o = 0; o < 4; ++o) {
                int k = jj - o;
                if (k >= 0 && k < 11) {
                    float w = gw[k];
                    aP[o]  = fmaf(w, pv, aP[o]);
                    aT[o]  = fmaf(w, tv, aT[o]);
                    aPP[o] = fmaf(w, pp, aPP[o]);
                    aTT[o] = fmaf(w, tt, aTT[o]);
                    aPT[o] = fmaf(w, pt, aPT[o]);
                }
            }
        }
        int base = r * HPW + q * 2;   // even -> 8B aligned
        {
            float2 v;
            v.x = __builtin_bit_cast(float, __floats2half2_rn(aP[0], aP[1]));
            v.y = __builtin_bit_cast(float, __floats2half2_rn(aP[2], aP[3]));
            *(float2*)&sHP[0 * FS + base] = v;
            v.x = __builtin_bit_cast(float, __floats2half2_rn(aT[0], aT[1]));
            v.y = __builtin_bit_cast(float, __floats2half2_rn(aT[2], aT[3]));
            *(float2*)&sHP[1 * FS + base] = v;
            v.x = __builtin_bit_cast(float, __floats2half2_rn(aPP[0], aPP[1]));
            v.y = __builtin_bit_cast(float, __floats2half2_rn(aPP[2], aPP[3]));
            *(float2*)&sHP[2 * FS + base] = v;
            v.x = __builtin_bit_cast(float, __floats2half2_rn(aTT[0], aTT[1]));
            v.y = __builtin_bit_cast(float, __floats2half2_rn(aTT[2], aTT[3]));
            *(float2*)&sHP[3 * FS + base] = v;
            v.x = __builtin_bit_cast(float, __floats2half2_rn(aPT[0], aPT[1]));
            v.y = __builtin_bit_cast(float, __floats2half2_rn(aPT[2], aPT[3]));
            *(float2*)&sHP[4 * FS + base] = v;
        }
    }
    __syncthreads();

    // ---- stage 3: vertical pass (packed fp16) + SSIM ----
    __half2 gwh[11];
    #pragma unroll
    for (int i = 0; i < 11; ++i) gwh[i] = __float2half2_rn(gw[i]);

    const int q  = tid & 15;       // x-quad: cols q*4 .. q*4+3
    const int y0 = (tid >> 4) * 2; // rows y0, y0+1
    __half2 acc[2][5][2];
    {
        __half2 z = __float2half2_rn(0.f);
        #pragma unroll
        for (int a = 0; a < 2; ++a)
            #pragma unroll
            for (int f = 0; f < 5; ++f) {
                acc[a][f][0] = z;
                acc[a][f][1] = z;
            }
    }

    #pragma unroll
    for (int f = 0; f < 5; ++f) {
        const float* col = &sHP[f * FS + q * 2];
        #pragma unroll
        for (int j = 0; j < 12; ++j) {        // rows y0..y0+11 cover both outputs
            float2 raw = *(const float2*)&col[(y0 + j) * HPW];
            __half2 ha = __builtin_bit_cast(__half2, raw.x);
            __half2 hb = __builtin_bit_cast(__half2, raw.y);
            if (j < 11) {
                acc[0][f][0] = __hfma2(gwh[j], ha, acc[0][f][0]);
                acc[0][f][1] = __hfma2(gwh[j], hb, acc[0][f][1]);
            }
            if (j >= 1) {
                acc[1][f][0] = __hfma2(gwh[j - 1], ha, acc[1][f][0]);
                acc[1][f][1] = __hfma2(gwh[j - 1], hb, acc[1][f][1]);
            }
        }
    }

    float ssim = 0.f;
    #pragma unroll
    for (int rr = 0; rr < 2; ++rr) {
        #pragma unroll
        for (int hh = 0; hh < 2; ++hh) {
            float2 m1 = __half22float2(acc[rr][0][hh]);
            float2 m2 = __half22float2(acc[rr][1][hh]);
            float2 cpp = __half22float2(acc[rr][2][hh]);
            float2 ctt = __half22float2(acc[rr][3][hh]);
            float2 cpt = __half22float2(acc[rr][4][hh]);
            #pragma unroll
            for (int e = 0; e < 2; ++e) {
                float mu1 = e ? m1.y : m1.x;
                float mu2 = e ? m2.y : m2.x;
                float vpp = e ? cpp.y : cpp.x;
                float vtt = e ? ctt.y : ctt.x;
                float vpt = e ? cpt.y : cpt.x;
                float mu1sq = mu1 * mu1;
                float mu2sq = mu2 * mu2;
                float mu12  = mu1 * mu2;
                float s1  = vpp - mu1sq;
                float s2  = vtt - mu2sq;
                float s12 = vpt - mu12;
                float num = (2.f * mu12 + SSIM_C1) * (2.f * s12 + SSIM_C2);
                float den = (mu1sq + mu2sq + SSIM_C1) * (s1 + s2 + SSIM_C2);
                ssim += num / den;
            }
        }
    }

    // ---- stage 4: block reduction, atomics ----
    #pragma unroll
    for (int off = 32; off > 0; off >>= 1) {
        mse  += __shfl_down(mse, off);
        ssim += __shfl_down(ssim, off);
    }
    const int wid = tid >> 6;
    if ((tid & 63) == 0) {
        red[0][wid] = mse;
        red[1][wid] = ssim;
    }
    __syncthreads();
    if (tid == 0) {
        float m = red[0][0] + red[0][1] + red[0][2] + red[0][3];
        float s = red[1][0] + red[1][1] + red[1][2] + red[1][3];
        atomicAdd(&ws[0], m);
        atomicAdd(&ws[1], s);
    }
}

__global__ void finalize_loss(const float* __restrict__ ws, float* __restrict__ out, float invN) {
    float mse  = ws[0] * invN;
    float ssim = ws[1] * invN;
    out[0] = mse + 0.01f * (1.f - ssim);
}

extern "C" void kernel_launch(void* const* d_in, const int* in_sizes, int n_in,
                              void* d_out, int out_size, void* d_ws, size_t ws_size,
                              hipStream_t stream) {
    const float* P = (const float*)d_in[0];
    const float* T = (const float*)d_in[1];
    float* out = (float*)d_out;
    float* ws  = (float*)d_ws;

    const int planes = in_sizes[0] / (WSZ * WSZ);   // 96 for (32,3,512,512)
    const float invN = 1.f / (float)in_sizes[0];

    hipMemsetAsync(ws, 0, 2 * sizeof(float), stream);
    dim3 grid(WSZ / TW, WSZ / TH, planes);
    fused_mse_ssim<<<grid, 256, 0, stream>>>(P, T, ws);
    finalize_loss<<<1, 1, 0, stream>>>(ws, out, invN);
}